// Round 7
// baseline (1115.456 us; speedup 1.0000x reference)
//
#include <hip/hip_runtime.h>
#include <hip/hip_cooperative_groups.h>

namespace cg = cooperative_groups;

#define U_NUM 50000
#define I_NUM 20000
#define F_DIM 64
#define N_EDGES 1000000
#define BATCH 131072

#define FP_U 200           // fine partitions: 256 rows each
#define FP_I 160           // fine partitions: 128 cols each
#define CAPF_U 5632        // mean 5120, +7 sigma
#define CAPF_I 6912        // mean 6400, +6.4 sigma
#define TILE 4096          // 40KB LDS -> 4 blocks/CU
#define NBU 245            // ceil(1M / 4096)
#define NBI 245
#define CVB 512            // grid-strided cvt blocks

// fp8 e4m3 (OCP) conversion. gfx950 (CDNA4) replaced the gfx940 unscaled
// cvt builtins with the scalef32 family (scale=1.0f -> exact conversion).
// Fallback chain: gfx950 scalef32 -> gfx940 unscaled -> software.
typedef float v2f __attribute__((ext_vector_type(2)));
typedef short v2s __attribute__((ext_vector_type(2)));

#if defined(__has_builtin)
#if __has_builtin(__builtin_amdgcn_cvt_scalef32_pk_f32_fp8) && __has_builtin(__builtin_amdgcn_cvt_scalef32_pk_fp8_f32)
#define HW_FP8_950 1
#elif __has_builtin(__builtin_amdgcn_cvt_pk_f32_fp8) && __has_builtin(__builtin_amdgcn_cvt_pk_fp8_f32)
#define HW_FP8_940 1
#endif
#endif

__device__ __forceinline__ void dec4(unsigned u, float* f) {
#if defined(HW_FP8_950)
    v2f lo = __builtin_amdgcn_cvt_scalef32_pk_f32_fp8(u, 1.0f, false);
    v2f hi = __builtin_amdgcn_cvt_scalef32_pk_f32_fp8(u, 1.0f, true);
    f[0] = lo.x; f[1] = lo.y; f[2] = hi.x; f[3] = hi.y;
#elif defined(HW_FP8_940)
    v2f lo = __builtin_amdgcn_cvt_pk_f32_fp8((int)u, false);
    v2f hi = __builtin_amdgcn_cvt_pk_f32_fp8((int)u, true);
    f[0] = lo.x; f[1] = lo.y; f[2] = hi.x; f[3] = hi.y;
#else
    #pragma unroll
    for (int i = 0; i < 4; i++) {
        unsigned v = (u >> (8 * i)) & 0xFFu;
        unsigned s = v >> 7, e = (v >> 3) & 15u, m = v & 7u;
        float mag = (e == 0) ? (float)m * 0.001953125f
                             : __uint_as_float(((e + 120u) << 23) | (m << 20));
        f[i] = s ? -mag : mag;
    }
#endif
}

#if !defined(HW_FP8_950) && !defined(HW_FP8_940)
__device__ __forceinline__ unsigned char enc1(float x) {
    unsigned s = (__float_as_uint(x) >> 31) << 7;
    float a = fabsf(x);
    if (a >= 448.f) return (unsigned char)(s | 0x7E);
    if (a < 0.015625f) {
        int m = __float2int_rn(a * 512.f);
        if (m >= 8) return (unsigned char)(s | 0x08);
        return (unsigned char)(s | m);
    }
    unsigned au = __float_as_uint(a);
    au += 0x7FFFFu + ((au >> 20) & 1u);
    int e = (int)(au >> 23) - 127;
    if (e > 8) return (unsigned char)(s | 0x7E);
    return (unsigned char)(s | ((unsigned)(e + 7) << 3) | ((au >> 20) & 7u));
}
#endif

__device__ __forceinline__ unsigned enc4(float a, float b, float c, float d) {
#if defined(HW_FP8_950)
    union { v2s s; unsigned u; } r;
    r.s.x = 0; r.s.y = 0;
    r.s = __builtin_amdgcn_cvt_scalef32_pk_fp8_f32(r.s, a, b, 1.0f, false);
    r.s = __builtin_amdgcn_cvt_scalef32_pk_fp8_f32(r.s, c, d, 1.0f, true);
    return r.u;
#elif defined(HW_FP8_940)
    int v = __builtin_amdgcn_cvt_pk_fp8_f32(a, b, 0, false);
    v = __builtin_amdgcn_cvt_pk_fp8_f32(c, d, v, true);
    return (unsigned)v;
#else
    return (unsigned)enc1(a) | ((unsigned)enc1(b) << 8)
         | ((unsigned)enc1(c) << 16) | ((unsigned)enc1(d) << 24);
#endif
}

__device__ __forceinline__ unsigned short f2b(float f) {
    unsigned b = __float_as_uint(f);
    b += 0x7FFFu + ((b >> 16) & 1u);
    return (unsigned short)(b >> 16);
}

// ---------------- single-pass fine-partition build (+ merged cvt) ------------
#define N_EU 800000
#define N_EI 320000
#define N_OU 800000
#define N_OI 320000
#define CVT_TOT (N_EU + N_EI + N_OU + N_OI)
__global__ void build_fine(const int* __restrict__ rows, const int* __restrict__ cols,
                           const float* __restrict__ uiv, const float* __restrict__ iuv,
                           int* __restrict__ fcurU, int2* __restrict__ fbufU,
                           int* __restrict__ fcurI, int2* __restrict__ fbufI,
                           const float* __restrict__ eU, const float* __restrict__ eI,
                           const float* __restrict__ oU, const float* __restrict__ oI,
                           unsigned* __restrict__ e8U, unsigned* __restrict__ e8I,
                           unsigned* __restrict__ o8U, unsigned* __restrict__ o8I)
{
    if (blockIdx.x >= NBU + NBI) {
        // grid-strided fp32->fp8 table conversion (independent work)
        for (int idx = (blockIdx.x - NBU - NBI) * 256 + threadIdx.x;
             idx < CVT_TOT; idx += CVB * 256) {
            const float* s; unsigned* d; int off; float sc;
            if (idx < N_EU)                      { s = eU; d = e8U; off = idx; sc = 128.f; }
            else if (idx < N_EU + N_EI)          { s = eI; d = e8I; off = idx - N_EU; sc = 128.f; }
            else if (idx < N_EU + N_EI + N_OU)   { s = oU; d = o8U; off = idx - N_EU - N_EI; sc = 1.f; }
            else                                 { s = oI; d = o8I; off = idx - N_EU - N_EI - N_OU; sc = 1.f; }
            float4 v = ((const float4*)s)[off];
            d[off] = enc4(v.x * sc, v.y * sc, v.z * sc, v.w * sc);
        }
        return;
    }

    __shared__ int2 rec[TILE];                  // 32 KB
    __shared__ unsigned char pid[TILE];         // 4 KB
    __shared__ int hist[256], scan[256], curs[256], delta[256];

    bool isU = blockIdx.x < NBU;
    int tb = isU ? blockIdx.x : blockIdx.x - NBU;
    int n0 = tb * TILE;
    int n  = min(TILE, N_EDGES - n0);
    int bins  = isU ? FP_U : FP_I;
    int capf  = isU ? CAPF_U : CAPF_I;
    int shift = isU ? 8 : 7;
    int* fcur = isU ? fcurU : fcurI;
    int2* fbuf = isU ? fbufU : fbufI;
    const int* keys = isU ? rows : cols;
    const int* srcs = isU ? cols : rows;
    const float* vals = isU ? uiv : iuv;

    hist[threadIdx.x] = 0;
    __syncthreads();

    // phase A: histogram by fine partition
    for (int t = threadIdx.x; t < n; t += 256)
        atomicAdd(&hist[keys[n0 + t] >> shift], 1);
    __syncthreads();

    // phase B: 256-wide LDS scan -> lbase; reserve global cursors
    int v = hist[threadIdx.x];
    scan[threadIdx.x] = v;
    __syncthreads();
    for (int off = 1; off < 256; off <<= 1) {
        int t = ((int)threadIdx.x >= off) ? scan[threadIdx.x - off] : 0;
        __syncthreads();
        scan[threadIdx.x] += t;
        __syncthreads();
    }
    int lbase = scan[threadIdx.x] - v;
    curs[threadIdx.x] = lbase;
    if ((int)threadIdx.x < bins) {
        int res = v ? atomicAdd(&fcur[threadIdx.x], v) : 0;
        delta[threadIdx.x] = threadIdx.x * capf + res - lbase;
    }
    __syncthreads();

    // phase C: re-read (L2-warm) and place partition-sorted in LDS
    for (int t = threadIdx.x; t < n; t += 256) {
        int key = keys[n0 + t];
        int src = srcs[n0 + t];
        float vv = vals[n0 + t];
        int b = key >> shift;
        int slot = atomicAdd(&curs[b], 1);
        int2 r;
        r.x = (int)(((unsigned)src << 16) | (unsigned)key);
        r.y = __float_as_int(vv);
        rec[slot] = r;
        pid[slot] = (unsigned char)b;
    }
    __syncthreads();

    // flush: consecutive slots -> consecutive global addresses per bin run
    for (int t = threadIdx.x; t < n; t += 256) {
        int b = pid[t];
        int a = delta[b] + t;
        if (a < (b + 1) * capf) fbuf[a] = rec[t];
    }
}

// ---------------- sort_csr: fine partition -> exact CSR (4B recs) + ptr/cnt --
__global__ void sort_csr(const int* __restrict__ fcurU, const int2* __restrict__ fbufU,
                         int* __restrict__ ptrU, int* __restrict__ cntU, unsigned* __restrict__ edgesU,
                         const int* __restrict__ fcurI, const int2* __restrict__ fbufI,
                         int* __restrict__ ptrI, int* __restrict__ cntI, unsigned* __restrict__ edgesI)
{
    __shared__ int hist[256], scan[256], curs[256];
    __shared__ int gbase_s;

    const int* fcur; const int2* fbuf; int* ptr; int* cnt; unsigned* edges;
    int fp, bins, capf, nrow;
    if (blockIdx.x < FP_U) {
        fcur = fcurU; fbuf = fbufU; ptr = ptrU; cnt = cntU; edges = edgesU;
        fp = blockIdx.x; bins = 256; capf = CAPF_U; nrow = U_NUM;
    } else {
        fcur = fcurI; fbuf = fbufI; ptr = ptrI; cnt = cntI; edges = edgesI;
        fp = blockIdx.x - FP_U; bins = 128; capf = CAPF_I; nrow = I_NUM;
    }

    int tid = threadIdx.x;
    if (tid == 0) gbase_s = 0;
    for (int i = tid; i < bins; i += 512) hist[i] = 0;
    __syncthreads();

    int contrib = (tid < fp) ? min(fcur[tid], capf) : 0;
    #pragma unroll
    for (int off = 32; off > 0; off >>= 1) contrib += __shfl_down(contrib, off, 64);
    if ((tid & 63) == 0 && contrib) atomicAdd(&gbase_s, contrib);

    int n = min(fcur[fp], capf);
    const int2* src = fbuf + (size_t)fp * capf;
    int mask = bins - 1;

    for (int t = tid; t < n; t += 512) {
        int dst = src[t].x & 0xFFFF;
        atomicAdd(&hist[dst & mask], 1);
    }
    __syncthreads();

    int v = (tid < bins) ? hist[tid] : 0;
    if (tid < 256) scan[tid] = v;
    __syncthreads();
    for (int off = 1; off < 256; off <<= 1) {
        int t = (tid >= off && tid < 256) ? scan[tid - off] : 0;
        __syncthreads();
        if (tid < 256) scan[tid] += t;
        __syncthreads();
    }
    int ex = (tid < 256) ? (scan[tid] - v) : 0;
    if (tid < 256) curs[tid] = ex;
    __syncthreads();
    int gbase = gbase_s;

    if (tid < bins) {
        int row = fp * bins + tid;
        if (row < nrow) {
            ptr[row] = gbase + ex;
            cnt[row] = v;
        }
    }

    for (int t = tid; t < n; t += 512) {
        int2 r = src[t];
        int dst = r.x & 0xFFFF;
        int pos = atomicAdd(&curs[dst & mask], 1);
        unsigned rec = ((unsigned)f2b(__int_as_float(r.y)) << 16)
                     | ((unsigned)r.x >> 16);
        edges[gbase + pos] = rec;
    }
}

// ---------------- SpMM row-group body (v4: 4 rows/wave, 16 lanes each) -------
template <int MODE>
__device__ __forceinline__ void spmm_row_group(
    int g, int h, int q,
    const int* __restrict__ ptrU, const int* __restrict__ cntU,
    const unsigned* __restrict__ edgesU, const unsigned* __restrict__ srcU,
    unsigned* __restrict__ dstU,
    const unsigned* __restrict__ l0U, const unsigned* __restrict__ l1U,
    const unsigned* __restrict__ l2U, unsigned* __restrict__ g8U,
    const int* __restrict__ ptrI, const int* __restrict__ cntI,
    const unsigned* __restrict__ edgesI, const unsigned* __restrict__ srcI,
    unsigned* __restrict__ dstI,
    const unsigned* __restrict__ l0I, const unsigned* __restrict__ l1I,
    const unsigned* __restrict__ l2I, unsigned* __restrict__ g8I)
{
    int gr = 4 * g + h;              // I-first global row index; always valid
    bool isU = gr >= I_NUM;
    int row = isU ? gr - I_NUM : gr;

    const int*  ptr   = isU ? ptrU   : ptrI;
    const int*  cnt   = isU ? cntU   : cntI;
    const unsigned* edges = isU ? edgesU : edgesI;
    const unsigned* semb  = isU ? srcU   : srcI;

    int begin = ptr[row];
    int len   = cnt[row];
    const unsigned* erow = edges + begin;

    float4 a0 = make_float4(0.f, 0.f, 0.f, 0.f);
    float4 a1 = make_float4(0.f, 0.f, 0.f, 0.f);
    float4 a2 = make_float4(0.f, 0.f, 0.f, 0.f);
    float4 a3 = make_float4(0.f, 0.f, 0.f, 0.f);
    int k = 0;
    for (; k + 4 <= len; k += 4) {
        unsigned r0 = erow[k];
        unsigned r1 = erow[k + 1];
        unsigned r2 = erow[k + 2];
        unsigned r3 = erow[k + 3];
        unsigned x0 = semb[((size_t)(r0 & 0xFFFFu) << 4) + q];
        unsigned x1 = semb[((size_t)(r1 & 0xFFFFu) << 4) + q];
        unsigned x2 = semb[((size_t)(r2 & 0xFFFFu) << 4) + q];
        unsigned x3 = semb[((size_t)(r3 & 0xFFFFu) << 4) + q];
        float v0 = __uint_as_float(r0 & 0xFFFF0000u);
        float v1 = __uint_as_float(r1 & 0xFFFF0000u);
        float v2 = __uint_as_float(r2 & 0xFFFF0000u);
        float v3 = __uint_as_float(r3 & 0xFFFF0000u);
        float f0[4], f1[4], f2[4], f3[4];
        dec4(x0, f0); dec4(x1, f1); dec4(x2, f2); dec4(x3, f3);
        a0.x += v0 * f0[0]; a0.y += v0 * f0[1]; a0.z += v0 * f0[2]; a0.w += v0 * f0[3];
        a1.x += v1 * f1[0]; a1.y += v1 * f1[1]; a1.z += v1 * f1[2]; a1.w += v1 * f1[3];
        a2.x += v2 * f2[0]; a2.y += v2 * f2[1]; a2.z += v2 * f2[2]; a2.w += v2 * f2[3];
        a3.x += v3 * f3[0]; a3.y += v3 * f3[1]; a3.z += v3 * f3[2]; a3.w += v3 * f3[3];
    }
    for (; k < len; k++) {
        unsigned r0 = erow[k];
        unsigned x0 = semb[((size_t)(r0 & 0xFFFFu) << 4) + q];
        float v0 = __uint_as_float(r0 & 0xFFFF0000u);
        float f0[4];
        dec4(x0, f0);
        a0.x += v0 * f0[0]; a0.y += v0 * f0[1]; a0.z += v0 * f0[2]; a0.w += v0 * f0[3];
    }
    float4 acc;
    acc.x = (a0.x + a1.x) + (a2.x + a3.x);
    acc.y = (a0.y + a1.y) + (a2.y + a3.y);
    acc.z = (a0.z + a1.z) + (a2.z + a3.z);
    acc.w = (a0.w + a1.w) + (a2.w + a3.w);

    size_t ro = ((size_t)row << 4) + q;
    if (MODE < 2) {
        unsigned* dst = isU ? dstU : dstI;
        dst[ro] = enc4(acc.x, acc.y, acc.z, acc.w);
    } else {
        const unsigned* l0 = isU ? l0U : l0I;
        const unsigned* l1 = isU ? l1U : l1I;
        const unsigned* l2 = isU ? l2U : l2I;
        unsigned* g8       = isU ? g8U : g8I;
        float e[4], b[4], c[4];
        dec4(l0[ro], e); dec4(l1[ro], b); dec4(l2[ro], c);
        const float third = 1.f / 3.f;
        float gx = 0.125f * (e[0] + 0.5f * b[0] + third * c[0] + 0.25f * acc.x);
        float gy = 0.125f * (e[1] + 0.5f * b[1] + third * c[1] + 0.25f * acc.y);
        float gz = 0.125f * (e[2] + 0.5f * b[2] + third * c[2] + 0.25f * acc.z);
        float gw = 0.125f * (e[3] + 0.5f * b[3] + third * c[3] + 0.25f * acc.w);
        g8[ro] = enc4(gx, gy, gz, gw);
    }
}

// Static LPT mapping over 17500 row-groups (I-groups 0..4999 @ ~200 edges,
// U-groups 5000..17499 @ ~80 edges) across 8192 waves:
//   wave < 5000       -> {I_w, U_{5000+w}}        (~280 edges)
//   5000 <= wave <7500-> 3 U-groups               (~240 edges)
//   wave >= 7500      -> idle (waits at grid sync)
template <int MODE>
__device__ __forceinline__ void spmm_phase(
    int wid, int h, int q,
    const int* ptrU, const int* cntU, const unsigned* edgesU, const unsigned* srcU,
    unsigned* dstU, const unsigned* l0U, const unsigned* l1U, const unsigned* l2U, unsigned* g8U,
    const int* ptrI, const int* cntI, const unsigned* edgesI, const unsigned* srcI,
    unsigned* dstI, const unsigned* l0I, const unsigned* l1I, const unsigned* l2I, unsigned* g8I)
{
#define SPMM_CALL(G) spmm_row_group<MODE>((G), h, q, ptrU,cntU,edgesU,srcU,dstU,l0U,l1U,l2U,g8U, \
                                          ptrI,cntI,edgesI,srcI,dstI,l0I,l1I,l2I,g8I)
    if (wid < 5000) {
        SPMM_CALL(wid);
        SPMM_CALL(5000 + wid);
    } else if (wid < 7500) {
        int b = 10000 + 3 * (wid - 5000);
        SPMM_CALL(b);
        SPMM_CALL(b + 1);
        SPMM_CALL(b + 2);
    }
#undef SPMM_CALL
}

// ---------------- fused 3-level SpMM: one cooperative dispatch ---------------
// 2048 blocks x 256 thr = exact co-residency at 8 waves/EU (<=64 VGPR forced).
// grid.sync() + threadfence between levels replaces 2 launch boundaries.
__global__ void __launch_bounds__(256, 8)
spmm_fused(const int* __restrict__ ptrU, const int* __restrict__ cntU,
           const unsigned* __restrict__ edgesU,
           const int* __restrict__ ptrI, const int* __restrict__ cntI,
           const unsigned* __restrict__ edgesI,
           const unsigned* __restrict__ e8U, const unsigned* __restrict__ e8I,
           unsigned* __restrict__ u1, unsigned* __restrict__ i1,
           unsigned* __restrict__ u2, unsigned* __restrict__ i2,
           unsigned* __restrict__ g8U, unsigned* __restrict__ g8I)
{
    cg::grid_group grid = cg::this_grid();
    int wid  = (blockIdx.x * blockDim.x + threadIdx.x) >> 6;
    int lane = threadIdx.x & 63;
    int h = lane >> 4, q = lane & 15;

    spmm_phase<0>(wid, h, q,
                  ptrU, cntU, edgesU, e8I, u1, nullptr, nullptr, nullptr, nullptr,
                  ptrI, cntI, edgesI, e8U, i1, nullptr, nullptr, nullptr, nullptr);
    __threadfence();
    grid.sync();
    spmm_phase<1>(wid, h, q,
                  ptrU, cntU, edgesU, i1, u2, nullptr, nullptr, nullptr, nullptr,
                  ptrI, cntI, edgesI, u1, i2, nullptr, nullptr, nullptr, nullptr);
    __threadfence();
    grid.sync();
    spmm_phase<2>(wid, h, q,
                  ptrU, cntU, edgesU, i2, nullptr, e8U, u1, u2, g8U,
                  ptrI, cntI, edgesI, u2, nullptr, e8I, i1, i2, g8I);
}

// ---------------- fallback: per-level kernel (round-6 proven path) -----------
template <int MODE>
__global__ void spmm_level(const int* __restrict__ ptrU, const int* __restrict__ cntU,
                           const unsigned* __restrict__ edgesU, const unsigned* __restrict__ srcU,
                           unsigned* __restrict__ dstU,
                           const unsigned* __restrict__ l0U, const unsigned* __restrict__ l1U,
                           const unsigned* __restrict__ l2U, unsigned* __restrict__ g8U,
                           const int* __restrict__ ptrI, const int* __restrict__ cntI,
                           const unsigned* __restrict__ edgesI, const unsigned* __restrict__ srcI,
                           unsigned* __restrict__ dstI,
                           const unsigned* __restrict__ l0I, const unsigned* __restrict__ l1I,
                           const unsigned* __restrict__ l2I, unsigned* __restrict__ g8I)
{
    int wave = (blockIdx.x * blockDim.x + threadIdx.x) >> 6;
    int lane = threadIdx.x & 63;
    int h = lane >> 4, q = lane & 15;
    if (wave >= (U_NUM + I_NUM) / 4) return;
    spmm_row_group<MODE>(wave, h, q,
                         ptrU, cntU, edgesU, srcU, dstU, l0U, l1U, l2U, g8U,
                         ptrI, cntI, edgesI, srcI, dstI, l0I, l1I, l2I, g8I);
}

// ---------------- contrastive loss v5: side-split, 8 samples/quarter ---------
__device__ __forceinline__ float dotq(const float* a, const float* b) {
    return a[0] * b[0] + a[1] * b[1] + a[2] * b[2] + a[3] * b[3];
}

__device__ __forceinline__ float sel4f(float a, float b, float c, float d, int k) {
    float lo = (k & 1) ? b : a;
    float hi = (k & 1) ? d : c;
    return (k & 2) ? hi : lo;
}

__global__ void __launch_bounds__(256, 2)
contrastive_side8(const unsigned* __restrict__ oldU, const unsigned* __restrict__ gcnU,
                  const int* __restrict__ userU, const int* __restrict__ iiU,
                  const int* __restrict__ ijU, const float* __restrict__ degU,
                  const unsigned* __restrict__ oldI, const unsigned* __restrict__ gcnI,
                  const int* __restrict__ userI, const int* __restrict__ iiI,
                  const int* __restrict__ ijI, const float* __restrict__ degI,
                  float* __restrict__ out)
{
    const int HALF = 1024;
    bool isU = blockIdx.x < HALF;
    const unsigned* old_ = isU ? oldU : oldI;
    const unsigned* gcn_ = isU ? gcnU : gcnI;
    const int* pu_  = isU ? userU : userI;
    const int* pii  = isU ? iiU   : iiI;
    const int* pij  = isU ? ijU   : ijI;
    const float* pdg = isU ? degU : degI;
    float inv = isU ? (1.f / U_NUM) : (1.f / I_NUM);
    int bid = isU ? blockIdx.x : blockIdx.x - HALF;

    int lane = threadIdx.x & 63;
    int sub  = lane >> 4;
    int ql   = lane & 15;
    int qg = (bid * blockDim.x + threadIdx.x) >> 4;   // quarter index within side
    int s0 = qg << 3;                                  // 8 samples per quarter

    int sel = ql >> 2;
    const int* p = (sel == 0) ? ((const int*)pu_) : (sel == 1) ? ((const int*)pii)
                 : (sel == 2) ? ((const int*)pij) : ((const int*)pdg);
    p += s0 + (ql & 3);
    int idxA = p[0];
    int idxB = p[4];

    int qb = sub << 4;
    unsigned Au[8], Ai[8], Aj[8];
    #pragma unroll
    for (int t = 0; t < 8; t++) {
        int src = (t < 4) ? idxA : idxB;
        int u = __shfl(src, qb + (t & 3), 64);
        int i = __shfl(src, qb + 4 + (t & 3), 64);
        int j = __shfl(src, qb + 8 + (t & 3), 64);
        Au[t] = old_[((size_t)u << 4) + ql];
        Ai[t] = gcn_[((size_t)i << 4) + ql];
        Aj[t] = gcn_[((size_t)j << 4) + ql];
    }

    float si[8], sj[8];
    #pragma unroll
    for (int t = 0; t < 8; t++) {
        float fu[4], fi[4], fj[4];
        dec4(Au[t], fu); dec4(Ai[t], fi); dec4(Aj[t], fj);
        si[t] = dotq(fu, fi); sj[t] = dotq(fu, fj);
    }

    #pragma unroll
    for (int off = 1; off < 16; off <<= 1) {
        #pragma unroll
        for (int t = 0; t < 8; t++) {
            si[t] += __shfl_xor(si[t], off, 64);
            sj[t] += __shfl_xor(sj[t], off, 64);
        }
    }

    int t3 = ql & 3;
    float dgA = __int_as_float(__shfl(idxA, qb + 12 + t3, 64));
    float dgB = __int_as_float(__shfl(idxB, qb + 12 + t3, 64));
    bool hi4 = (ql & 4) != 0;
    float siv = hi4 ? sel4f(si[4], si[5], si[6], si[7], t3)
                    : sel4f(si[0], si[1], si[2], si[3], t3);
    float sjv = hi4 ? sel4f(sj[4], sj[5], sj[6], sj[7], t3)
                    : sel4f(sj[0], sj[1], sj[2], sj[3], t3);
    float dg = hi4 ? dgB : dgA;

    const float S = 0.0625f;    // o8 scale 1, g8 = 16*gcn -> si_raw = 16*si
    siv *= S; sjv *= S;
    float m = fmaxf(siv, sjv);
    float lse = m + logf(expf(siv - m) + expf(sjv - m));
    float acc = (ql < 8) ? -(siv - lse) * dg * inv : 0.f;

    #pragma unroll
    for (int off = 32; off > 0; off >>= 1) acc += __shfl_down(acc, off, 64);
    __shared__ float wsum[4];
    if (lane == 0) wsum[threadIdx.x >> 6] = acc;
    __syncthreads();
    if (threadIdx.x == 0)
        atomicAdd(out, wsum[0] + wsum[1] + wsum[2] + wsum[3]);
}

extern "C" void kernel_launch(void* const* d_in, const int* in_sizes, int n_in,
                              void* d_out, int out_size, void* d_ws, size_t ws_size,
                              hipStream_t stream)
{
    const float* embed_user = (const float*)d_in[0];
    const float* embed_item = (const float*)d_in[1];
    const float* old_U      = (const float*)d_in[2];
    const float* old_I      = (const float*)d_in[3];
    const int*   erow       = (const int*)d_in[4];
    const int*   ecol       = (const int*)d_in[5];
    const float* ui_vals    = (const float*)d_in[6];
    const float* iu_vals    = (const float*)d_in[7];
    const int*   user       = (const int*)d_in[8];
    const int*   item_i     = (const int*)d_in[9];
    const int*   item_j     = (const int*)d_in[10];
    const float* degU       = (const float*)d_in[11];
    const int*   user_      = (const int*)d_in[13];
    const int*   item_i_    = (const int*)d_in[14];
    const int*   item_j_    = (const int*)d_in[15];
    const float* degI       = (const float*)d_in[16];

    const size_t UF = (size_t)U_NUM * F_DIM;
    const size_t IF = (size_t)I_NUM * F_DIM;
    const size_t FRECU = (size_t)FP_U * CAPF_U;   // 1,126,400
    const size_t FRECI = (size_t)FP_I * CAPF_I;   // 1,105,920

    int2*  fbufU  = (int2*)d_ws;                       // 9.0 MB
    int2*  fbufI  = fbufU + FRECU;                     // 8.8 MB
    unsigned* edgesU = (unsigned*)(fbufI + FRECI);     // 4 MB
    unsigned* edgesI = edgesU + N_EDGES;               // 4 MB
    char* cur = (char*)(edgesI + N_EDGES);
    unsigned* e8U = (unsigned*)cur; cur += UF;
    unsigned* e8I = (unsigned*)cur; cur += IF;
    unsigned* o8U = (unsigned*)cur; cur += UF;
    unsigned* o8I = (unsigned*)cur; cur += IF;
    unsigned* u1_8 = (unsigned*)cur; cur += UF;
    unsigned* u2_8 = (unsigned*)cur; cur += UF;
    unsigned* i1_8 = (unsigned*)cur; cur += IF;
    unsigned* i2_8 = (unsigned*)cur; cur += IF;
    unsigned* g8U  = (unsigned*)cur; cur += UF;
    unsigned* g8I  = (unsigned*)cur; cur += IF;
    int* fcurU = (int*)cur;            // 256 slots (200 used)
    int* fcurI = fcurU + 256;          // 256 slots (160 used)
    int* ptrU  = fcurI + 256;
    int* cntUa = ptrU + U_NUM;
    int* ptrI  = cntUa + U_NUM;
    int* cntIa = ptrI + I_NUM;
    // total ~48 MB

    dim3 blk(256);
    const int bf_blocks  = NBU + NBI + CVB;            // 1002
    const int st_blocks  = FP_U + FP_I;                // 360

    hipMemsetAsync(fcurU, 0, 512 * sizeof(int), stream);
    hipMemsetAsync(d_out, 0, sizeof(float), stream);

    build_fine<<<bf_blocks, blk, 0, stream>>>(erow, ecol, ui_vals, iu_vals,
                                              fcurU, fbufU, fcurI, fbufI,
                                              embed_user, embed_item, old_U, old_I,
                                              e8U, e8I, o8U, o8I);
    sort_csr<<<st_blocks, dim3(512), 0, stream>>>(fcurU, fbufU, ptrU, cntUa, edgesU,
                                                  fcurI, fbufI, ptrI, cntIa, edgesI);

    // Fused L1+L2+L3: one cooperative dispatch, grid.sync between levels.
    {
        void* cargs[] = {
            (void*)&ptrU, (void*)&cntUa, (void*)&edgesU,
            (void*)&ptrI, (void*)&cntIa, (void*)&edgesI,
            (void*)&e8U, (void*)&e8I,
            (void*)&u1_8, (void*)&i1_8, (void*)&u2_8, (void*)&i2_8,
            (void*)&g8U, (void*)&g8I
        };
        hipError_t cerr = hipLaunchCooperativeKernel((void*)spmm_fused,
                                                     dim3(2048), dim3(256),
                                                     cargs, 0, stream);
        if (cerr != hipSuccess) {
            // fallback: proven 3-launch path (round 6)
            const int spmm_blocks = (U_NUM + I_NUM) / 16;  // 4375
            spmm_level<0><<<spmm_blocks, blk, 0, stream>>>(
                ptrU, cntUa, edgesU, e8I, u1_8, nullptr, nullptr, nullptr, nullptr,
                ptrI, cntIa, edgesI, e8U, i1_8, nullptr, nullptr, nullptr, nullptr);
            spmm_level<1><<<spmm_blocks, blk, 0, stream>>>(
                ptrU, cntUa, edgesU, i1_8, u2_8, nullptr, nullptr, nullptr, nullptr,
                ptrI, cntIa, edgesI, u1_8, i2_8, nullptr, nullptr, nullptr, nullptr);
            spmm_level<2><<<spmm_blocks, blk, 0, stream>>>(
                ptrU, cntUa, edgesU, i2_8, nullptr, e8U, u1_8, u2_8, g8U,
                ptrI, cntIa, edgesI, u2_8, nullptr, e8I, i1_8, i2_8, g8I);
        }
    }

    contrastive_side8<<<2048, blk, 0, stream>>>(o8U, g8U, user, item_i, item_j, degU,
                                                o8I, g8I, user_, item_i_, item_j_, degI,
                                                (float*)d_out);
}

// Round 8
// 274.439 us; speedup vs baseline: 4.0645x; 4.0645x over previous
//
#include <hip/hip_runtime.h>

#define U_NUM 50000
#define I_NUM 20000
#define F_DIM 64
#define N_EDGES 1000000
#define BATCH 131072

#define FP_U 200           // fine partitions: 256 rows each
#define FP_I 160           // fine partitions: 128 cols each
#define CAPF_U 5632        // mean 5120, +7 sigma
#define CAPF_I 6912        // mean 6400, +6.4 sigma
#define TILE 4096          // 40KB LDS -> 4 blocks/CU
#define NBU 245            // ceil(1M / 4096)
#define NBI 245
#define CVB 512            // grid-strided cvt blocks

// fp8 e4m3 (OCP) conversion. gfx950 (CDNA4) replaced the gfx940 unscaled
// cvt builtins with the scalef32 family (scale=1.0f -> exact conversion).
// Fallback chain: gfx950 scalef32 -> gfx940 unscaled -> software.
typedef float v2f __attribute__((ext_vector_type(2)));
typedef short v2s __attribute__((ext_vector_type(2)));

#if defined(__has_builtin)
#if __has_builtin(__builtin_amdgcn_cvt_scalef32_pk_f32_fp8) && __has_builtin(__builtin_amdgcn_cvt_scalef32_pk_fp8_f32)
#define HW_FP8_950 1
#elif __has_builtin(__builtin_amdgcn_cvt_pk_f32_fp8) && __has_builtin(__builtin_amdgcn_cvt_pk_fp8_f32)
#define HW_FP8_940 1
#endif
#endif

__device__ __forceinline__ void dec4(unsigned u, float* f) {
#if defined(HW_FP8_950)
    v2f lo = __builtin_amdgcn_cvt_scalef32_pk_f32_fp8(u, 1.0f, false);
    v2f hi = __builtin_amdgcn_cvt_scalef32_pk_f32_fp8(u, 1.0f, true);
    f[0] = lo.x; f[1] = lo.y; f[2] = hi.x; f[3] = hi.y;
#elif defined(HW_FP8_940)
    v2f lo = __builtin_amdgcn_cvt_pk_f32_fp8((int)u, false);
    v2f hi = __builtin_amdgcn_cvt_pk_f32_fp8((int)u, true);
    f[0] = lo.x; f[1] = lo.y; f[2] = hi.x; f[3] = hi.y;
#else
    #pragma unroll
    for (int i = 0; i < 4; i++) {
        unsigned v = (u >> (8 * i)) & 0xFFu;
        unsigned s = v >> 7, e = (v >> 3) & 15u, m = v & 7u;
        float mag = (e == 0) ? (float)m * 0.001953125f
                             : __uint_as_float(((e + 120u) << 23) | (m << 20));
        f[i] = s ? -mag : mag;
    }
#endif
}

#if !defined(HW_FP8_950) && !defined(HW_FP8_940)
__device__ __forceinline__ unsigned char enc1(float x) {
    unsigned s = (__float_as_uint(x) >> 31) << 7;
    float a = fabsf(x);
    if (a >= 448.f) return (unsigned char)(s | 0x7E);
    if (a < 0.015625f) {
        int m = __float2int_rn(a * 512.f);
        if (m >= 8) return (unsigned char)(s | 0x08);
        return (unsigned char)(s | m);
    }
    unsigned au = __float_as_uint(a);
    au += 0x7FFFFu + ((au >> 20) & 1u);
    int e = (int)(au >> 23) - 127;
    if (e > 8) return (unsigned char)(s | 0x7E);
    return (unsigned char)(s | ((unsigned)(e + 7) << 3) | ((au >> 20) & 7u));
}
#endif

__device__ __forceinline__ unsigned enc4(float a, float b, float c, float d) {
#if defined(HW_FP8_950)
    union { v2s s; unsigned u; } r;
    r.s.x = 0; r.s.y = 0;
    r.s = __builtin_amdgcn_cvt_scalef32_pk_fp8_f32(r.s, a, b, 1.0f, false);
    r.s = __builtin_amdgcn_cvt_scalef32_pk_fp8_f32(r.s, c, d, 1.0f, true);
    return r.u;
#elif defined(HW_FP8_940)
    int v = __builtin_amdgcn_cvt_pk_fp8_f32(a, b, 0, false);
    v = __builtin_amdgcn_cvt_pk_fp8_f32(c, d, v, true);
    return (unsigned)v;
#else
    return (unsigned)enc1(a) | ((unsigned)enc1(b) << 8)
         | ((unsigned)enc1(c) << 16) | ((unsigned)enc1(d) << 24);
#endif
}

__device__ __forceinline__ unsigned short f2b(float f) {
    unsigned b = __float_as_uint(f);
    b += 0x7FFFu + ((b >> 16) & 1u);
    return (unsigned short)(b >> 16);
}

// ---------------- single-pass fine-partition build (+ merged cvt) ------------
#define N_EU 800000
#define N_EI 320000
#define N_OU 800000
#define N_OI 320000
#define CVT_TOT (N_EU + N_EI + N_OU + N_OI)
__global__ void build_fine(const int* __restrict__ rows, const int* __restrict__ cols,
                           const float* __restrict__ uiv, const float* __restrict__ iuv,
                           int* __restrict__ fcurU, int2* __restrict__ fbufU,
                           int* __restrict__ fcurI, int2* __restrict__ fbufI,
                           const float* __restrict__ eU, const float* __restrict__ eI,
                           const float* __restrict__ oU, const float* __restrict__ oI,
                           unsigned* __restrict__ e8U, unsigned* __restrict__ e8I,
                           unsigned* __restrict__ o8U, unsigned* __restrict__ o8I)
{
    if (blockIdx.x >= NBU + NBI) {
        // grid-strided fp32->fp8 table conversion (independent work)
        for (int idx = (blockIdx.x - NBU - NBI) * 256 + threadIdx.x;
             idx < CVT_TOT; idx += CVB * 256) {
            const float* s; unsigned* d; int off; float sc;
            if (idx < N_EU)                      { s = eU; d = e8U; off = idx; sc = 128.f; }
            else if (idx < N_EU + N_EI)          { s = eI; d = e8I; off = idx - N_EU; sc = 128.f; }
            else if (idx < N_EU + N_EI + N_OU)   { s = oU; d = o8U; off = idx - N_EU - N_EI; sc = 1.f; }
            else                                 { s = oI; d = o8I; off = idx - N_EU - N_EI - N_OU; sc = 1.f; }
            float4 v = ((const float4*)s)[off];
            d[off] = enc4(v.x * sc, v.y * sc, v.z * sc, v.w * sc);
        }
        return;
    }

    __shared__ int2 rec[TILE];                  // 32 KB
    __shared__ unsigned char pid[TILE];         // 4 KB
    __shared__ int hist[256], scan[256], curs[256], delta[256];

    bool isU = blockIdx.x < NBU;
    int tb = isU ? blockIdx.x : blockIdx.x - NBU;
    int n0 = tb * TILE;
    int n  = min(TILE, N_EDGES - n0);
    int bins  = isU ? FP_U : FP_I;
    int capf  = isU ? CAPF_U : CAPF_I;
    int shift = isU ? 8 : 7;
    int* fcur = isU ? fcurU : fcurI;
    int2* fbuf = isU ? fbufU : fbufI;
    const int* keys = isU ? rows : cols;
    const int* srcs = isU ? cols : rows;
    const float* vals = isU ? uiv : iuv;

    hist[threadIdx.x] = 0;
    __syncthreads();

    // phase A: histogram by fine partition
    for (int t = threadIdx.x; t < n; t += 256)
        atomicAdd(&hist[keys[n0 + t] >> shift], 1);
    __syncthreads();

    // phase B: 256-wide LDS scan -> lbase; reserve global cursors
    int v = hist[threadIdx.x];
    scan[threadIdx.x] = v;
    __syncthreads();
    for (int off = 1; off < 256; off <<= 1) {
        int t = ((int)threadIdx.x >= off) ? scan[threadIdx.x - off] : 0;
        __syncthreads();
        scan[threadIdx.x] += t;
        __syncthreads();
    }
    int lbase = scan[threadIdx.x] - v;
    curs[threadIdx.x] = lbase;
    if ((int)threadIdx.x < bins) {
        int res = v ? atomicAdd(&fcur[threadIdx.x], v) : 0;
        delta[threadIdx.x] = threadIdx.x * capf + res - lbase;
    }
    __syncthreads();

    // phase C: re-read (L2-warm) and place partition-sorted in LDS
    for (int t = threadIdx.x; t < n; t += 256) {
        int key = keys[n0 + t];
        int src = srcs[n0 + t];
        float vv = vals[n0 + t];
        int b = key >> shift;
        int slot = atomicAdd(&curs[b], 1);
        int2 r;
        r.x = (int)(((unsigned)src << 16) | (unsigned)key);
        r.y = __float_as_int(vv);
        rec[slot] = r;
        pid[slot] = (unsigned char)b;
    }
    __syncthreads();

    // flush: consecutive slots -> consecutive global addresses per bin run
    for (int t = threadIdx.x; t < n; t += 256) {
        int b = pid[t];
        int a = delta[b] + t;
        if (a < (b + 1) * capf) fbuf[a] = rec[t];
    }
}

// ---------------- sort_csr: fine partition -> exact CSR (4B recs) + ptr/cnt --
__global__ void sort_csr(const int* __restrict__ fcurU, const int2* __restrict__ fbufU,
                         int* __restrict__ ptrU, int* __restrict__ cntU, unsigned* __restrict__ edgesU,
                         const int* __restrict__ fcurI, const int2* __restrict__ fbufI,
                         int* __restrict__ ptrI, int* __restrict__ cntI, unsigned* __restrict__ edgesI)
{
    __shared__ int hist[256], scan[256], curs[256];
    __shared__ int gbase_s;

    const int* fcur; const int2* fbuf; int* ptr; int* cnt; unsigned* edges;
    int fp, bins, capf, nrow;
    if (blockIdx.x < FP_U) {
        fcur = fcurU; fbuf = fbufU; ptr = ptrU; cnt = cntU; edges = edgesU;
        fp = blockIdx.x; bins = 256; capf = CAPF_U; nrow = U_NUM;
    } else {
        fcur = fcurI; fbuf = fbufI; ptr = ptrI; cnt = cntI; edges = edgesI;
        fp = blockIdx.x - FP_U; bins = 128; capf = CAPF_I; nrow = I_NUM;
    }

    int tid = threadIdx.x;
    if (tid == 0) gbase_s = 0;
    for (int i = tid; i < bins; i += 512) hist[i] = 0;
    __syncthreads();

    int contrib = (tid < fp) ? min(fcur[tid], capf) : 0;
    #pragma unroll
    for (int off = 32; off > 0; off >>= 1) contrib += __shfl_down(contrib, off, 64);
    if ((tid & 63) == 0 && contrib) atomicAdd(&gbase_s, contrib);

    int n = min(fcur[fp], capf);
    const int2* src = fbuf + (size_t)fp * capf;
    int mask = bins - 1;

    for (int t = tid; t < n; t += 512) {
        int dst = src[t].x & 0xFFFF;
        atomicAdd(&hist[dst & mask], 1);
    }
    __syncthreads();

    int v = (tid < bins) ? hist[tid] : 0;
    if (tid < 256) scan[tid] = v;
    __syncthreads();
    for (int off = 1; off < 256; off <<= 1) {
        int t = (tid >= off && tid < 256) ? scan[tid - off] : 0;
        __syncthreads();
        if (tid < 256) scan[tid] += t;
        __syncthreads();
    }
    int ex = (tid < 256) ? (scan[tid] - v) : 0;
    if (tid < 256) curs[tid] = ex;
    __syncthreads();
    int gbase = gbase_s;

    if (tid < bins) {
        int row = fp * bins + tid;
        if (row < nrow) {
            ptr[row] = gbase + ex;
            cnt[row] = v;
        }
    }

    for (int t = tid; t < n; t += 512) {
        int2 r = src[t];
        int dst = r.x & 0xFFFF;
        int pos = atomicAdd(&curs[dst & mask], 1);
        unsigned rec = ((unsigned)f2b(__int_as_float(r.y)) << 16)
                     | ((unsigned)r.x >> 16);
        edges[gbase + pos] = rec;
    }
}

// ---------------- side-split gather SpMM (v5) --------------------------------
// One launch per (level, side): the active gather table (e8U 3.2MB or
// e8I/i_k 1.25MB) fits a 4MB XCD L2 alone, vs 4.5MB+streams mixed before
// (75% hit). Body identical to the proven v4 (4 rows/wave, 16 lanes each,
// 4-edge unroll, no cross-lane reduce, 256B coalesced store).
template <int MODE>
__global__ void spmm_side(const int* __restrict__ ptr, const int* __restrict__ cnt,
                          const unsigned* __restrict__ edges, const unsigned* __restrict__ semb,
                          unsigned* __restrict__ dst,
                          const unsigned* __restrict__ l0, const unsigned* __restrict__ l1,
                          const unsigned* __restrict__ l2, unsigned* __restrict__ g8,
                          int nrow)
{
    int wave = (blockIdx.x * blockDim.x + threadIdx.x) >> 6;
    int lane = threadIdx.x & 63;
    int h    = lane >> 4;            // row slot 0..3 within the wave
    int q    = lane & 15;            // dword slice of the 64B row

    int row = 4 * wave + h;
    if (row >= nrow) return;

    int begin = ptr[row];
    int len   = cnt[row];
    const unsigned* erow = edges + begin;

    float4 a0 = make_float4(0.f, 0.f, 0.f, 0.f);
    float4 a1 = make_float4(0.f, 0.f, 0.f, 0.f);
    float4 a2 = make_float4(0.f, 0.f, 0.f, 0.f);
    float4 a3 = make_float4(0.f, 0.f, 0.f, 0.f);
    int k = 0;
    for (; k + 4 <= len; k += 4) {
        unsigned r0 = erow[k];
        unsigned r1 = erow[k + 1];
        unsigned r2 = erow[k + 2];
        unsigned r3 = erow[k + 3];
        unsigned x0 = semb[((size_t)(r0 & 0xFFFFu) << 4) + q];
        unsigned x1 = semb[((size_t)(r1 & 0xFFFFu) << 4) + q];
        unsigned x2 = semb[((size_t)(r2 & 0xFFFFu) << 4) + q];
        unsigned x3 = semb[((size_t)(r3 & 0xFFFFu) << 4) + q];
        float v0 = __uint_as_float(r0 & 0xFFFF0000u);
        float v1 = __uint_as_float(r1 & 0xFFFF0000u);
        float v2 = __uint_as_float(r2 & 0xFFFF0000u);
        float v3 = __uint_as_float(r3 & 0xFFFF0000u);
        float f0[4], f1[4], f2[4], f3[4];
        dec4(x0, f0); dec4(x1, f1); dec4(x2, f2); dec4(x3, f3);
        a0.x += v0 * f0[0]; a0.y += v0 * f0[1]; a0.z += v0 * f0[2]; a0.w += v0 * f0[3];
        a1.x += v1 * f1[0]; a1.y += v1 * f1[1]; a1.z += v1 * f1[2]; a1.w += v1 * f1[3];
        a2.x += v2 * f2[0]; a2.y += v2 * f2[1]; a2.z += v2 * f2[2]; a2.w += v2 * f2[3];
        a3.x += v3 * f3[0]; a3.y += v3 * f3[1]; a3.z += v3 * f3[2]; a3.w += v3 * f3[3];
    }
    for (; k < len; k++) {
        unsigned r0 = erow[k];
        unsigned x0 = semb[((size_t)(r0 & 0xFFFFu) << 4) + q];
        float v0 = __uint_as_float(r0 & 0xFFFF0000u);
        float f0[4];
        dec4(x0, f0);
        a0.x += v0 * f0[0]; a0.y += v0 * f0[1]; a0.z += v0 * f0[2]; a0.w += v0 * f0[3];
    }
    float4 acc;
    acc.x = (a0.x + a1.x) + (a2.x + a3.x);
    acc.y = (a0.y + a1.y) + (a2.y + a3.y);
    acc.z = (a0.z + a1.z) + (a2.z + a3.z);
    acc.w = (a0.w + a1.w) + (a2.w + a3.w);

    size_t ro = ((size_t)row << 4) + q;
    if (MODE < 2) {
        dst[ro] = enc4(acc.x, acc.y, acc.z, acc.w);
    } else {
        float e[4], b[4], c[4];
        dec4(l0[ro], e); dec4(l1[ro], b); dec4(l2[ro], c);
        const float third = 1.f / 3.f;
        float gx = 0.125f * (e[0] + 0.5f * b[0] + third * c[0] + 0.25f * acc.x);
        float gy = 0.125f * (e[1] + 0.5f * b[1] + third * c[1] + 0.25f * acc.y);
        float gz = 0.125f * (e[2] + 0.5f * b[2] + third * c[2] + 0.25f * acc.z);
        float gw = 0.125f * (e[3] + 0.5f * b[3] + third * c[3] + 0.25f * acc.w);
        g8[ro] = enc4(gx, gy, gz, gw);
    }
}

// ---------------- contrastive loss v5: side-split, 8 samples/quarter ---------
__device__ __forceinline__ float dotq(const float* a, const float* b) {
    return a[0] * b[0] + a[1] * b[1] + a[2] * b[2] + a[3] * b[3];
}

__device__ __forceinline__ float sel4f(float a, float b, float c, float d, int k) {
    float lo = (k & 1) ? b : a;
    float hi = (k & 1) ? d : c;
    return (k & 2) ? hi : lo;
}

__global__ void __launch_bounds__(256, 2)
contrastive_side8(const unsigned* __restrict__ oldU, const unsigned* __restrict__ gcnU,
                  const int* __restrict__ userU, const int* __restrict__ iiU,
                  const int* __restrict__ ijU, const float* __restrict__ degU,
                  const unsigned* __restrict__ oldI, const unsigned* __restrict__ gcnI,
                  const int* __restrict__ userI, const int* __restrict__ iiI,
                  const int* __restrict__ ijI, const float* __restrict__ degI,
                  float* __restrict__ out)
{
    const int HALF = 1024;
    bool isU = blockIdx.x < HALF;
    const unsigned* old_ = isU ? oldU : oldI;
    const unsigned* gcn_ = isU ? gcnU : gcnI;
    const int* pu_  = isU ? userU : userI;
    const int* pii  = isU ? iiU   : iiI;
    const int* pij  = isU ? ijU   : ijI;
    const float* pdg = isU ? degU : degI;
    float inv = isU ? (1.f / U_NUM) : (1.f / I_NUM);
    int bid = isU ? blockIdx.x : blockIdx.x - HALF;

    int lane = threadIdx.x & 63;
    int sub  = lane >> 4;
    int ql   = lane & 15;
    int qg = (bid * blockDim.x + threadIdx.x) >> 4;   // quarter index within side
    int s0 = qg << 3;                                  // 8 samples per quarter

    int sel = ql >> 2;
    const int* p = (sel == 0) ? ((const int*)pu_) : (sel == 1) ? ((const int*)pii)
                 : (sel == 2) ? ((const int*)pij) : ((const int*)pdg);
    p += s0 + (ql & 3);
    int idxA = p[0];
    int idxB = p[4];

    int qb = sub << 4;
    unsigned Au[8], Ai[8], Aj[8];
    #pragma unroll
    for (int t = 0; t < 8; t++) {
        int src = (t < 4) ? idxA : idxB;
        int u = __shfl(src, qb + (t & 3), 64);
        int i = __shfl(src, qb + 4 + (t & 3), 64);
        int j = __shfl(src, qb + 8 + (t & 3), 64);
        Au[t] = old_[((size_t)u << 4) + ql];
        Ai[t] = gcn_[((size_t)i << 4) + ql];
        Aj[t] = gcn_[((size_t)j << 4) + ql];
    }

    float si[8], sj[8];
    #pragma unroll
    for (int t = 0; t < 8; t++) {
        float fu[4], fi[4], fj[4];
        dec4(Au[t], fu); dec4(Ai[t], fi); dec4(Aj[t], fj);
        si[t] = dotq(fu, fi); sj[t] = dotq(fu, fj);
    }

    #pragma unroll
    for (int off = 1; off < 16; off <<= 1) {
        #pragma unroll
        for (int t = 0; t < 8; t++) {
            si[t] += __shfl_xor(si[t], off, 64);
            sj[t] += __shfl_xor(sj[t], off, 64);
        }
    }

    int t3 = ql & 3;
    float dgA = __int_as_float(__shfl(idxA, qb + 12 + t3, 64));
    float dgB = __int_as_float(__shfl(idxB, qb + 12 + t3, 64));
    bool hi4 = (ql & 4) != 0;
    float siv = hi4 ? sel4f(si[4], si[5], si[6], si[7], t3)
                    : sel4f(si[0], si[1], si[2], si[3], t3);
    float sjv = hi4 ? sel4f(sj[4], sj[5], sj[6], sj[7], t3)
                    : sel4f(sj[0], sj[1], sj[2], sj[3], t3);
    float dg = hi4 ? dgB : dgA;

    const float S = 0.0625f;    // o8 scale 1, g8 = 16*gcn -> si_raw = 16*si
    siv *= S; sjv *= S;
    float m = fmaxf(siv, sjv);
    float lse = m + logf(expf(siv - m) + expf(sjv - m));
    float acc = (ql < 8) ? -(siv - lse) * dg * inv : 0.f;

    #pragma unroll
    for (int off = 32; off > 0; off >>= 1) acc += __shfl_down(acc, off, 64);
    __shared__ float wsum[4];
    if (lane == 0) wsum[threadIdx.x >> 6] = acc;
    __syncthreads();
    if (threadIdx.x == 0)
        atomicAdd(out, wsum[0] + wsum[1] + wsum[2] + wsum[3]);
}

extern "C" void kernel_launch(void* const* d_in, const int* in_sizes, int n_in,
                              void* d_out, int out_size, void* d_ws, size_t ws_size,
                              hipStream_t stream)
{
    const float* embed_user = (const float*)d_in[0];
    const float* embed_item = (const float*)d_in[1];
    const float* old_U      = (const float*)d_in[2];
    const float* old_I      = (const float*)d_in[3];
    const int*   erow       = (const int*)d_in[4];
    const int*   ecol       = (const int*)d_in[5];
    const float* ui_vals    = (const float*)d_in[6];
    const float* iu_vals    = (const float*)d_in[7];
    const int*   user       = (const int*)d_in[8];
    const int*   item_i     = (const int*)d_in[9];
    const int*   item_j     = (const int*)d_in[10];
    const float* degU       = (const float*)d_in[11];
    const int*   user_      = (const int*)d_in[13];
    const int*   item_i_    = (const int*)d_in[14];
    const int*   item_j_    = (const int*)d_in[15];
    const float* degI       = (const float*)d_in[16];

    const size_t UF = (size_t)U_NUM * F_DIM;
    const size_t IF = (size_t)I_NUM * F_DIM;
    const size_t FRECU = (size_t)FP_U * CAPF_U;   // 1,126,400
    const size_t FRECI = (size_t)FP_I * CAPF_I;   // 1,105,920

    int2*  fbufU  = (int2*)d_ws;                       // 9.0 MB
    int2*  fbufI  = fbufU + FRECU;                     // 8.8 MB
    unsigned* edgesU = (unsigned*)(fbufI + FRECI);     // 4 MB
    unsigned* edgesI = edgesU + N_EDGES;               // 4 MB
    char* cur = (char*)(edgesI + N_EDGES);
    unsigned* e8U = (unsigned*)cur; cur += UF;
    unsigned* e8I = (unsigned*)cur; cur += IF;
    unsigned* o8U = (unsigned*)cur; cur += UF;
    unsigned* o8I = (unsigned*)cur; cur += IF;
    unsigned* u1_8 = (unsigned*)cur; cur += UF;
    unsigned* u2_8 = (unsigned*)cur; cur += UF;
    unsigned* i1_8 = (unsigned*)cur; cur += IF;
    unsigned* i2_8 = (unsigned*)cur; cur += IF;
    unsigned* g8U  = (unsigned*)cur; cur += UF;
    unsigned* g8I  = (unsigned*)cur; cur += IF;
    int* fcurU = (int*)cur;            // 256 slots (200 used)
    int* fcurI = fcurU + 256;          // 256 slots (160 used)
    int* ptrU  = fcurI + 256;
    int* cntUa = ptrU + U_NUM;
    int* ptrI  = cntUa + U_NUM;
    int* cntIa = ptrI + I_NUM;
    // total ~48 MB

    dim3 blk(256);
    const int bf_blocks  = NBU + NBI + CVB;            // 1002
    const int st_blocks  = FP_U + FP_I;                // 360
    const int ub = U_NUM / 16;                         // 3125 blocks (U side)
    const int ib = I_NUM / 16;                         // 1250 blocks (I side)

    hipMemsetAsync(fcurU, 0, 512 * sizeof(int), stream);
    hipMemsetAsync(d_out, 0, sizeof(float), stream);

    build_fine<<<bf_blocks, blk, 0, stream>>>(erow, ecol, ui_vals, iu_vals,
                                              fcurU, fbufU, fcurI, fbufI,
                                              embed_user, embed_item, old_U, old_I,
                                              e8U, e8I, o8U, o8I);
    sort_csr<<<st_blocks, dim3(512), 0, stream>>>(fcurU, fbufU, ptrU, cntUa, edgesU,
                                                  fcurI, fbufI, ptrI, cntIa, edgesI);

    // Side-split levels: each launch's gather table is L2-resident.
    // i1 = A_iu @ e8U ; u1 = A_ui @ e8I
    spmm_side<0><<<ib, blk, 0, stream>>>(ptrI, cntIa, edgesI, e8U, i1_8,
                                         nullptr, nullptr, nullptr, nullptr, I_NUM);
    spmm_side<0><<<ub, blk, 0, stream>>>(ptrU, cntUa, edgesU, e8I, u1_8,
                                         nullptr, nullptr, nullptr, nullptr, U_NUM);
    // i2 = A_iu @ u1 ; u2 = A_ui @ i1
    spmm_side<1><<<ib, blk, 0, stream>>>(ptrI, cntIa, edgesI, u1_8, i2_8,
                                         nullptr, nullptr, nullptr, nullptr, I_NUM);
    spmm_side<1><<<ub, blk, 0, stream>>>(ptrU, cntUa, edgesU, i1_8, u2_8,
                                         nullptr, nullptr, nullptr, nullptr, U_NUM);
    // g8I: acc = i3 = A_iu @ u2, blended with e8I,i1,i2
    spmm_side<2><<<ib, blk, 0, stream>>>(ptrI, cntIa, edgesI, u2_8, nullptr,
                                         e8I, i1_8, i2_8, g8I, I_NUM);
    // g8U: acc = u3 = A_ui @ i2, blended with e8U,u1,u2
    spmm_side<2><<<ub, blk, 0, stream>>>(ptrU, cntUa, edgesU, i2_8, nullptr,
                                         e8U, u1_8, u2_8, g8U, U_NUM);

    contrastive_side8<<<2048, blk, 0, stream>>>(o8U, g8U, user, item_i, item_j, degU,
                                                o8I, g8I, user_, item_i_, item_j_, degI,
                                                (float*)d_out);
}

// Round 9
// 259.121 us; speedup vs baseline: 4.3048x; 1.0591x over previous
//
#include <hip/hip_runtime.h>

#define U_NUM 50000
#define I_NUM 20000
#define F_DIM 64
#define N_EDGES 1000000
#define BATCH 131072

#define FP_U 200           // fine partitions: 256 rows each
#define FP_I 160           // fine partitions: 128 cols each
#define CAPF_U 5632        // mean 5120, +7 sigma
#define CAPF_I 6912        // mean 6400, +6.4 sigma
#define TILE 4096          // 40KB LDS -> 4 blocks/CU
#define NBU 245            // ceil(1M / 4096)
#define NBI 245
#define CVB 512            // grid-strided cvt blocks

// fp8 e4m3 (OCP) conversion. gfx950 (CDNA4) replaced the gfx940 unscaled
// cvt builtins with the scalef32 family (scale=1.0f -> exact conversion).
// Fallback chain: gfx950 scalef32 -> gfx940 unscaled -> software.
typedef float v2f __attribute__((ext_vector_type(2)));
typedef short v2s __attribute__((ext_vector_type(2)));

#if defined(__has_builtin)
#if __has_builtin(__builtin_amdgcn_cvt_scalef32_pk_f32_fp8) && __has_builtin(__builtin_amdgcn_cvt_scalef32_pk_fp8_f32)
#define HW_FP8_950 1
#elif __has_builtin(__builtin_amdgcn_cvt_pk_f32_fp8) && __has_builtin(__builtin_amdgcn_cvt_pk_fp8_f32)
#define HW_FP8_940 1
#endif
#endif

__device__ __forceinline__ void dec4(unsigned u, float* f) {
#if defined(HW_FP8_950)
    v2f lo = __builtin_amdgcn_cvt_scalef32_pk_f32_fp8(u, 1.0f, false);
    v2f hi = __builtin_amdgcn_cvt_scalef32_pk_f32_fp8(u, 1.0f, true);
    f[0] = lo.x; f[1] = lo.y; f[2] = hi.x; f[3] = hi.y;
#elif defined(HW_FP8_940)
    v2f lo = __builtin_amdgcn_cvt_pk_f32_fp8((int)u, false);
    v2f hi = __builtin_amdgcn_cvt_pk_f32_fp8((int)u, true);
    f[0] = lo.x; f[1] = lo.y; f[2] = hi.x; f[3] = hi.y;
#else
    #pragma unroll
    for (int i = 0; i < 4; i++) {
        unsigned v = (u >> (8 * i)) & 0xFFu;
        unsigned s = v >> 7, e = (v >> 3) & 15u, m = v & 7u;
        float mag = (e == 0) ? (float)m * 0.001953125f
                             : __uint_as_float(((e + 120u) << 23) | (m << 20));
        f[i] = s ? -mag : mag;
    }
#endif
}

#if !defined(HW_FP8_950) && !defined(HW_FP8_940)
__device__ __forceinline__ unsigned char enc1(float x) {
    unsigned s = (__float_as_uint(x) >> 31) << 7;
    float a = fabsf(x);
    if (a >= 448.f) return (unsigned char)(s | 0x7E);
    if (a < 0.015625f) {
        int m = __float2int_rn(a * 512.f);
        if (m >= 8) return (unsigned char)(s | 0x08);
        return (unsigned char)(s | m);
    }
    unsigned au = __float_as_uint(a);
    au += 0x7FFFFu + ((au >> 20) & 1u);
    int e = (int)(au >> 23) - 127;
    if (e > 8) return (unsigned char)(s | 0x7E);
    return (unsigned char)(s | ((unsigned)(e + 7) << 3) | ((au >> 20) & 7u));
}
#endif

__device__ __forceinline__ unsigned enc4(float a, float b, float c, float d) {
#if defined(HW_FP8_950)
    union { v2s s; unsigned u; } r;
    r.s.x = 0; r.s.y = 0;
    r.s = __builtin_amdgcn_cvt_scalef32_pk_fp8_f32(r.s, a, b, 1.0f, false);
    r.s = __builtin_amdgcn_cvt_scalef32_pk_fp8_f32(r.s, c, d, 1.0f, true);
    return r.u;
#elif defined(HW_FP8_940)
    int v = __builtin_amdgcn_cvt_pk_fp8_f32(a, b, 0, false);
    v = __builtin_amdgcn_cvt_pk_fp8_f32(c, d, v, true);
    return (unsigned)v;
#else
    return (unsigned)enc1(a) | ((unsigned)enc1(b) << 8)
         | ((unsigned)enc1(c) << 16) | ((unsigned)enc1(d) << 24);
#endif
}

__device__ __forceinline__ unsigned short f2b(float f) {
    unsigned b = __float_as_uint(f);
    b += 0x7FFFu + ((b >> 16) & 1u);
    return (unsigned short)(b >> 16);
}

// ---------------- single-pass fine-partition build (+ merged cvt) ------------
#define N_EU 800000
#define N_EI 320000
#define N_OU 800000
#define N_OI 320000
#define CVT_TOT (N_EU + N_EI + N_OU + N_OI)
__global__ void build_fine(const int* __restrict__ rows, const int* __restrict__ cols,
                           const float* __restrict__ uiv, const float* __restrict__ iuv,
                           int* __restrict__ fcurU, int2* __restrict__ fbufU,
                           int* __restrict__ fcurI, int2* __restrict__ fbufI,
                           const float* __restrict__ eU, const float* __restrict__ eI,
                           const float* __restrict__ oU, const float* __restrict__ oI,
                           unsigned* __restrict__ e8U, unsigned* __restrict__ e8I,
                           unsigned* __restrict__ o8U, unsigned* __restrict__ o8I)
{
    if (blockIdx.x >= NBU + NBI) {
        // grid-strided fp32->fp8 table conversion (independent work)
        for (int idx = (blockIdx.x - NBU - NBI) * 256 + threadIdx.x;
             idx < CVT_TOT; idx += CVB * 256) {
            const float* s; unsigned* d; int off; float sc;
            if (idx < N_EU)                      { s = eU; d = e8U; off = idx; sc = 128.f; }
            else if (idx < N_EU + N_EI)          { s = eI; d = e8I; off = idx - N_EU; sc = 128.f; }
            else if (idx < N_EU + N_EI + N_OU)   { s = oU; d = o8U; off = idx - N_EU - N_EI; sc = 1.f; }
            else                                 { s = oI; d = o8I; off = idx - N_EU - N_EI - N_OU; sc = 1.f; }
            float4 v = ((const float4*)s)[off];
            d[off] = enc4(v.x * sc, v.y * sc, v.z * sc, v.w * sc);
        }
        return;
    }

    __shared__ int2 rec[TILE];                  // 32 KB
    __shared__ unsigned char pid[TILE];         // 4 KB
    __shared__ int hist[256], scan[256], curs[256], delta[256];

    bool isU = blockIdx.x < NBU;
    int tb = isU ? blockIdx.x : blockIdx.x - NBU;
    int n0 = tb * TILE;
    int n  = min(TILE, N_EDGES - n0);
    int bins  = isU ? FP_U : FP_I;
    int capf  = isU ? CAPF_U : CAPF_I;
    int shift = isU ? 8 : 7;
    int* fcur = isU ? fcurU : fcurI;
    int2* fbuf = isU ? fbufU : fbufI;
    const int* keys = isU ? rows : cols;
    const int* srcs = isU ? cols : rows;
    const float* vals = isU ? uiv : iuv;

    hist[threadIdx.x] = 0;
    __syncthreads();

    // phase A: histogram by fine partition
    for (int t = threadIdx.x; t < n; t += 256)
        atomicAdd(&hist[keys[n0 + t] >> shift], 1);
    __syncthreads();

    // phase B: 256-wide LDS scan -> lbase; reserve global cursors
    int v = hist[threadIdx.x];
    scan[threadIdx.x] = v;
    __syncthreads();
    for (int off = 1; off < 256; off <<= 1) {
        int t = ((int)threadIdx.x >= off) ? scan[threadIdx.x - off] : 0;
        __syncthreads();
        scan[threadIdx.x] += t;
        __syncthreads();
    }
    int lbase = scan[threadIdx.x] - v;
    curs[threadIdx.x] = lbase;
    if ((int)threadIdx.x < bins) {
        int res = v ? atomicAdd(&fcur[threadIdx.x], v) : 0;
        delta[threadIdx.x] = threadIdx.x * capf + res - lbase;
    }
    __syncthreads();

    // phase C: re-read (L2-warm) and place partition-sorted in LDS
    for (int t = threadIdx.x; t < n; t += 256) {
        int key = keys[n0 + t];
        int src = srcs[n0 + t];
        float vv = vals[n0 + t];
        int b = key >> shift;
        int slot = atomicAdd(&curs[b], 1);
        int2 r;
        r.x = (int)(((unsigned)src << 16) | (unsigned)key);
        r.y = __float_as_int(vv);
        rec[slot] = r;
        pid[slot] = (unsigned char)b;
    }
    __syncthreads();

    // flush: consecutive slots -> consecutive global addresses per bin run
    for (int t = threadIdx.x; t < n; t += 256) {
        int b = pid[t];
        int a = delta[b] + t;
        if (a < (b + 1) * capf) fbuf[a] = rec[t];
    }
}

// ---------------- sort_csr: fine partition -> exact CSR (4B recs) + ptr/cnt --
__global__ void sort_csr(const int* __restrict__ fcurU, const int2* __restrict__ fbufU,
                         int* __restrict__ ptrU, int* __restrict__ cntU, unsigned* __restrict__ edgesU,
                         const int* __restrict__ fcurI, const int2* __restrict__ fbufI,
                         int* __restrict__ ptrI, int* __restrict__ cntI, unsigned* __restrict__ edgesI)
{
    __shared__ int hist[256], scan[256], curs[256];
    __shared__ int gbase_s;

    const int* fcur; const int2* fbuf; int* ptr; int* cnt; unsigned* edges;
    int fp, bins, capf, nrow;
    if (blockIdx.x < FP_U) {
        fcur = fcurU; fbuf = fbufU; ptr = ptrU; cnt = cntU; edges = edgesU;
        fp = blockIdx.x; bins = 256; capf = CAPF_U; nrow = U_NUM;
    } else {
        fcur = fcurI; fbuf = fbufI; ptr = ptrI; cnt = cntI; edges = edgesI;
        fp = blockIdx.x - FP_U; bins = 128; capf = CAPF_I; nrow = I_NUM;
    }

    int tid = threadIdx.x;
    if (tid == 0) gbase_s = 0;
    for (int i = tid; i < bins; i += 512) hist[i] = 0;
    __syncthreads();

    int contrib = (tid < fp) ? min(fcur[tid], capf) : 0;
    #pragma unroll
    for (int off = 32; off > 0; off >>= 1) contrib += __shfl_down(contrib, off, 64);
    if ((tid & 63) == 0 && contrib) atomicAdd(&gbase_s, contrib);

    int n = min(fcur[fp], capf);
    const int2* src = fbuf + (size_t)fp * capf;
    int mask = bins - 1;

    for (int t = tid; t < n; t += 512) {
        int dst = src[t].x & 0xFFFF;
        atomicAdd(&hist[dst & mask], 1);
    }
    __syncthreads();

    int v = (tid < bins) ? hist[tid] : 0;
    if (tid < 256) scan[tid] = v;
    __syncthreads();
    for (int off = 1; off < 256; off <<= 1) {
        int t = (tid >= off && tid < 256) ? scan[tid - off] : 0;
        __syncthreads();
        if (tid < 256) scan[tid] += t;
        __syncthreads();
    }
    int ex = (tid < 256) ? (scan[tid] - v) : 0;
    if (tid < 256) curs[tid] = ex;
    __syncthreads();
    int gbase = gbase_s;

    if (tid < bins) {
        int row = fp * bins + tid;
        if (row < nrow) {
            ptr[row] = gbase + ex;
            cnt[row] = v;
        }
    }

    for (int t = tid; t < n; t += 512) {
        int2 r = src[t];
        int dst = r.x & 0xFFFF;
        int pos = atomicAdd(&curs[dst & mask], 1);
        unsigned rec = ((unsigned)f2b(__int_as_float(r.y)) << 16)
                     | ((unsigned)r.x >> 16);
        edges[gbase + pos] = rec;
    }
}

// ---------------- fused-level gather SpMM v4: 4 rows per wave ----------------
// Four rows per wave, 16 lanes each = 4 fully independent dependency chains,
// 4-edge unroll per chain -> 16 gathers in flight per wave. No cross-lane
// reduce (each 16-lane group owns its whole row); epilogue runs on all 64
// lanes; store is one 256B coalesced write per wave. I-rows (deg 50) first =
// LPT + phase-separates the gather tables.
template <int MODE>
__global__ void spmm_level(const int* __restrict__ ptrU, const int* __restrict__ cntU,
                           const unsigned* __restrict__ edgesU, const unsigned* __restrict__ srcU,
                           unsigned* __restrict__ dstU,
                           const unsigned* __restrict__ l0U, const unsigned* __restrict__ l1U,
                           const unsigned* __restrict__ l2U, unsigned* __restrict__ g8U,
                           const int* __restrict__ ptrI, const int* __restrict__ cntI,
                           const unsigned* __restrict__ edgesI, const unsigned* __restrict__ srcI,
                           unsigned* __restrict__ dstI,
                           const unsigned* __restrict__ l0I, const unsigned* __restrict__ l1I,
                           const unsigned* __restrict__ l2I, unsigned* __restrict__ g8I)
{
    int wave = (blockIdx.x * blockDim.x + threadIdx.x) >> 6;
    int lane = threadIdx.x & 63;
    int h    = lane >> 4;            // row slot 0..3 within the wave
    int q    = lane & 15;            // dword slice of the 64B row

    int gr = 4 * wave + h;           // I-first global row index
    bool isU = gr >= I_NUM;
    int row = isU ? gr - I_NUM : gr;
    if (isU && row >= U_NUM) return;

    const int*  ptr   = isU ? ptrU   : ptrI;
    const int*  cnt   = isU ? cntU   : cntI;
    const unsigned* edges = isU ? edgesU : edgesI;
    const unsigned* semb  = isU ? srcU   : srcI;

    int begin = ptr[row];
    int len   = cnt[row];
    const unsigned* erow = edges + begin;

    float4 a0 = make_float4(0.f, 0.f, 0.f, 0.f);
    float4 a1 = make_float4(0.f, 0.f, 0.f, 0.f);
    float4 a2 = make_float4(0.f, 0.f, 0.f, 0.f);
    float4 a3 = make_float4(0.f, 0.f, 0.f, 0.f);
    int k = 0;
    for (; k + 4 <= len; k += 4) {
        unsigned r0 = erow[k];
        unsigned r1 = erow[k + 1];
        unsigned r2 = erow[k + 2];
        unsigned r3 = erow[k + 3];
        unsigned x0 = semb[((size_t)(r0 & 0xFFFFu) << 4) + q];
        unsigned x1 = semb[((size_t)(r1 & 0xFFFFu) << 4) + q];
        unsigned x2 = semb[((size_t)(r2 & 0xFFFFu) << 4) + q];
        unsigned x3 = semb[((size_t)(r3 & 0xFFFFu) << 4) + q];
        float v0 = __uint_as_float(r0 & 0xFFFF0000u);
        float v1 = __uint_as_float(r1 & 0xFFFF0000u);
        float v2 = __uint_as_float(r2 & 0xFFFF0000u);
        float v3 = __uint_as_float(r3 & 0xFFFF0000u);
        float f0[4], f1[4], f2[4], f3[4];
        dec4(x0, f0); dec4(x1, f1); dec4(x2, f2); dec4(x3, f3);
        a0.x += v0 * f0[0]; a0.y += v0 * f0[1]; a0.z += v0 * f0[2]; a0.w += v0 * f0[3];
        a1.x += v1 * f1[0]; a1.y += v1 * f1[1]; a1.z += v1 * f1[2]; a1.w += v1 * f1[3];
        a2.x += v2 * f2[0]; a2.y += v2 * f2[1]; a2.z += v2 * f2[2]; a2.w += v2 * f2[3];
        a3.x += v3 * f3[0]; a3.y += v3 * f3[1]; a3.z += v3 * f3[2]; a3.w += v3 * f3[3];
    }
    for (; k < len; k++) {
        unsigned r0 = erow[k];
        unsigned x0 = semb[((size_t)(r0 & 0xFFFFu) << 4) + q];
        float v0 = __uint_as_float(r0 & 0xFFFF0000u);
        float f0[4];
        dec4(x0, f0);
        a0.x += v0 * f0[0]; a0.y += v0 * f0[1]; a0.z += v0 * f0[2]; a0.w += v0 * f0[3];
    }
    float4 acc;
    acc.x = (a0.x + a1.x) + (a2.x + a3.x);
    acc.y = (a0.y + a1.y) + (a2.y + a3.y);
    acc.z = (a0.z + a1.z) + (a2.z + a3.z);
    acc.w = (a0.w + a1.w) + (a2.w + a3.w);

    size_t ro = ((size_t)row << 4) + q;
    if (MODE < 2) {
        unsigned* dst = isU ? dstU : dstI;
        dst[ro] = enc4(acc.x, acc.y, acc.z, acc.w);
    } else {
        const unsigned* l0 = isU ? l0U : l0I;
        const unsigned* l1 = isU ? l1U : l1I;
        const unsigned* l2 = isU ? l2U : l2I;
        unsigned* g8       = isU ? g8U : g8I;
        float e[4], b[4], c[4];
        dec4(l0[ro], e); dec4(l1[ro], b); dec4(l2[ro], c);
        const float third = 1.f / 3.f;
        float gx = 0.125f * (e[0] + 0.5f * b[0] + third * c[0] + 0.25f * acc.x);
        float gy = 0.125f * (e[1] + 0.5f * b[1] + third * c[1] + 0.25f * acc.y);
        float gz = 0.125f * (e[2] + 0.5f * b[2] + third * c[2] + 0.25f * acc.z);
        float gw = 0.125f * (e[3] + 0.5f * b[3] + third * c[3] + 0.25f * acc.w);
        g8[ro] = enc4(gx, gy, gz, gw);
    }
}

// ---------------- contrastive loss v5: side-split, 8 samples/quarter ---------
__device__ __forceinline__ float dotq(const float* a, const float* b) {
    return a[0] * b[0] + a[1] * b[1] + a[2] * b[2] + a[3] * b[3];
}

__device__ __forceinline__ float sel4f(float a, float b, float c, float d, int k) {
    float lo = (k & 1) ? b : a;
    float hi = (k & 1) ? d : c;
    return (k & 2) ? hi : lo;
}

__global__ void __launch_bounds__(256, 2)
contrastive_side8(const unsigned* __restrict__ oldU, const unsigned* __restrict__ gcnU,
                  const int* __restrict__ userU, const int* __restrict__ iiU,
                  const int* __restrict__ ijU, const float* __restrict__ degU,
                  const unsigned* __restrict__ oldI, const unsigned* __restrict__ gcnI,
                  const int* __restrict__ userI, const int* __restrict__ iiI,
                  const int* __restrict__ ijI, const float* __restrict__ degI,
                  float* __restrict__ out)
{
    const int HALF = 1024;
    bool isU = blockIdx.x < HALF;
    const unsigned* old_ = isU ? oldU : oldI;
    const unsigned* gcn_ = isU ? gcnU : gcnI;
    const int* pu_  = isU ? userU : userI;
    const int* pii  = isU ? iiU   : iiI;
    const int* pij  = isU ? ijU   : ijI;
    const float* pdg = isU ? degU : degI;
    float inv = isU ? (1.f / U_NUM) : (1.f / I_NUM);
    int bid = isU ? blockIdx.x : blockIdx.x - HALF;

    int lane = threadIdx.x & 63;
    int sub  = lane >> 4;
    int ql   = lane & 15;
    int qg = (bid * blockDim.x + threadIdx.x) >> 4;   // quarter index within side
    int s0 = qg << 3;                                  // 8 samples per quarter

    int sel = ql >> 2;
    const int* p = (sel == 0) ? ((const int*)pu_) : (sel == 1) ? ((const int*)pii)
                 : (sel == 2) ? ((const int*)pij) : ((const int*)pdg);
    p += s0 + (ql & 3);
    int idxA = p[0];
    int idxB = p[4];

    int qb = sub << 4;
    unsigned Au[8], Ai[8], Aj[8];
    #pragma unroll
    for (int t = 0; t < 8; t++) {
        int src = (t < 4) ? idxA : idxB;
        int u = __shfl(src, qb + (t & 3), 64);
        int i = __shfl(src, qb + 4 + (t & 3), 64);
        int j = __shfl(src, qb + 8 + (t & 3), 64);
        Au[t] = old_[((size_t)u << 4) + ql];
        Ai[t] = gcn_[((size_t)i << 4) + ql];
        Aj[t] = gcn_[((size_t)j << 4) + ql];
    }

    float si[8], sj[8];
    #pragma unroll
    for (int t = 0; t < 8; t++) {
        float fu[4], fi[4], fj[4];
        dec4(Au[t], fu); dec4(Ai[t], fi); dec4(Aj[t], fj);
        si[t] = dotq(fu, fi); sj[t] = dotq(fu, fj);
    }

    #pragma unroll
    for (int off = 1; off < 16; off <<= 1) {
        #pragma unroll
        for (int t = 0; t < 8; t++) {
            si[t] += __shfl_xor(si[t], off, 64);
            sj[t] += __shfl_xor(sj[t], off, 64);
        }
    }

    int t3 = ql & 3;
    float dgA = __int_as_float(__shfl(idxA, qb + 12 + t3, 64));
    float dgB = __int_as_float(__shfl(idxB, qb + 12 + t3, 64));
    bool hi4 = (ql & 4) != 0;
    float siv = hi4 ? sel4f(si[4], si[5], si[6], si[7], t3)
                    : sel4f(si[0], si[1], si[2], si[3], t3);
    float sjv = hi4 ? sel4f(sj[4], sj[5], sj[6], sj[7], t3)
                    : sel4f(sj[0], sj[1], sj[2], sj[3], t3);
    float dg = hi4 ? dgB : dgA;

    const float S = 0.0625f;    // o8 scale 1, g8 = 16*gcn -> si_raw = 16*si
    siv *= S; sjv *= S;
    float m = fmaxf(siv, sjv);
    float lse = m + logf(expf(siv - m) + expf(sjv - m));
    float acc = (ql < 8) ? -(siv - lse) * dg * inv : 0.f;

    #pragma unroll
    for (int off = 32; off > 0; off >>= 1) acc += __shfl_down(acc, off, 64);
    __shared__ float wsum[4];
    if (lane == 0) wsum[threadIdx.x >> 6] = acc;
    __syncthreads();
    if (threadIdx.x == 0)
        atomicAdd(out, wsum[0] + wsum[1] + wsum[2] + wsum[3]);
}

extern "C" void kernel_launch(void* const* d_in, const int* in_sizes, int n_in,
                              void* d_out, int out_size, void* d_ws, size_t ws_size,
                              hipStream_t stream)
{
    const float* embed_user = (const float*)d_in[0];
    const float* embed_item = (const float*)d_in[1];
    const float* old_U      = (const float*)d_in[2];
    const float* old_I      = (const float*)d_in[3];
    const int*   erow       = (const int*)d_in[4];
    const int*   ecol       = (const int*)d_in[5];
    const float* ui_vals    = (const float*)d_in[6];
    const float* iu_vals    = (const float*)d_in[7];
    const int*   user       = (const int*)d_in[8];
    const int*   item_i     = (const int*)d_in[9];
    const int*   item_j     = (const int*)d_in[10];
    const float* degU       = (const float*)d_in[11];
    const int*   user_      = (const int*)d_in[13];
    const int*   item_i_    = (const int*)d_in[14];
    const int*   item_j_    = (const int*)d_in[15];
    const float* degI       = (const float*)d_in[16];

    const size_t UF = (size_t)U_NUM * F_DIM;
    const size_t IF = (size_t)I_NUM * F_DIM;
    const size_t FRECU = (size_t)FP_U * CAPF_U;   // 1,126,400
    const size_t FRECI = (size_t)FP_I * CAPF_I;   // 1,105,920

    int2*  fbufU  = (int2*)d_ws;                       // 9.0 MB
    int2*  fbufI  = fbufU + FRECU;                     // 8.8 MB
    unsigned* edgesU = (unsigned*)(fbufI + FRECI);     // 4 MB
    unsigned* edgesI = edgesU + N_EDGES;               // 4 MB
    char* cur = (char*)(edgesI + N_EDGES);
    unsigned* e8U = (unsigned*)cur; cur += UF;
    unsigned* e8I = (unsigned*)cur; cur += IF;
    unsigned* o8U = (unsigned*)cur; cur += UF;
    unsigned* o8I = (unsigned*)cur; cur += IF;
    unsigned* u1_8 = (unsigned*)cur; cur += UF;
    unsigned* u2_8 = (unsigned*)cur; cur += UF;
    unsigned* i1_8 = (unsigned*)cur; cur += IF;
    unsigned* i2_8 = (unsigned*)cur; cur += IF;
    unsigned* g8U  = (unsigned*)cur; cur += UF;
    unsigned* g8I  = (unsigned*)cur; cur += IF;
    int* fcurU = (int*)cur;            // 256 slots (200 used)
    int* fcurI = fcurU + 256;          // 256 slots (160 used)
    int* ptrU  = fcurI + 256;
    int* cntUa = ptrU + U_NUM;
    int* ptrI  = cntUa + U_NUM;
    int* cntIa = ptrI + I_NUM;
    // total ~48 MB

    dim3 blk(256);
    const int bf_blocks  = NBU + NBI + CVB;            // 1002
    const int st_blocks  = FP_U + FP_I;                // 360
    const int spmm_blocks = (U_NUM + I_NUM) / 16;      // 4375 (4 rows/wave)

    hipMemsetAsync(fcurU, 0, 512 * sizeof(int), stream);
    hipMemsetAsync(d_out, 0, sizeof(float), stream);

    build_fine<<<bf_blocks, blk, 0, stream>>>(erow, ecol, ui_vals, iu_vals,
                                              fcurU, fbufU, fcurI, fbufI,
                                              embed_user, embed_item, old_U, old_I,
                                              e8U, e8I, o8U, o8I);
    sort_csr<<<st_blocks, dim3(512), 0, stream>>>(fcurU, fbufU, ptrU, cntUa, edgesU,
                                                  fcurI, fbufI, ptrI, cntIa, edgesI);

    // L1: u1_8 = enc(128*u1) ; i1_8 = enc(128*i1)
    spmm_level<0><<<spmm_blocks, blk, 0, stream>>>(
        ptrU, cntUa, edgesU, e8I, u1_8, nullptr, nullptr, nullptr, nullptr,
        ptrI, cntIa, edgesI, e8U, i1_8, nullptr, nullptr, nullptr, nullptr);
    // L2: u2_8 = enc(128*u2) ; i2_8 = enc(128*i2)
    spmm_level<1><<<spmm_blocks, blk, 0, stream>>>(
        ptrU, cntUa, edgesU, i1_8, u2_8, nullptr, nullptr, nullptr, nullptr,
        ptrI, cntIa, edgesI, u1_8, i2_8, nullptr, nullptr, nullptr, nullptr);
    // L3: g8 = enc(0.125*(l0 + 0.5*l1 + (1/3)*l2 + 0.25*acc)) = enc(16*gcn)
    spmm_level<2><<<spmm_blocks, blk, 0, stream>>>(
        ptrU, cntUa, edgesU, i2_8, nullptr, e8U, u1_8, u2_8, g8U,
        ptrI, cntIa, edgesI, u2_8, nullptr, e8I, i1_8, i2_8, g8I);

    contrastive_side8<<<2048, blk, 0, stream>>>(o8U, g8U, user, item_i, item_j, degU,
                                                o8I, g8I, user_, item_i_, item_j_, degI,
                                                (float*)d_out);
}